// Round 1
// baseline (4349.659 us; speedup 1.0000x reference)
//
#include <hip/hip_runtime.h>
#include <math.h>

#define T_SEQ 2048
#define HID 2048
#define FFN 7168
#define NH 16
#define NKV 4
#define HD 128
#define NE 8
#define EPSV 1e-5f

typedef unsigned short u16;
typedef __bf16 bf16x8 __attribute__((ext_vector_type(8)));
typedef float f32x4 __attribute__((ext_vector_type(4)));

__device__ __forceinline__ u16 f2bf(float f) {
  unsigned int b = __float_as_uint(f);
  b += 0x7FFFu + ((b >> 16) & 1u);
  return (u16)(b >> 16);
}
__device__ __forceinline__ float bf2f(u16 u) {
  return __uint_as_float(((unsigned int)u) << 16);
}

// stage 16 bf16 (already bf16 in global) -> LDS
__device__ __forceinline__ void stage_a16(const u16* ap, u16* dst) {
  float4 a0 = ((const float4*)ap)[0];
  float4 a1 = ((const float4*)ap)[1];
  ((float4*)dst)[0] = a0;
  ((float4*)dst)[1] = a1;
}
// stage 16 fp32 weights -> bf16 -> LDS
__device__ __forceinline__ void stage_b16(const float* bp, u16* dst) {
  float4 b0 = ((const float4*)bp)[0];
  float4 b1 = ((const float4*)bp)[1];
  float4 b2 = ((const float4*)bp)[2];
  float4 b3 = ((const float4*)bp)[3];
  union { u16 u[16]; float4 f[2]; } pk;
  pk.u[0]=f2bf(b0.x); pk.u[1]=f2bf(b0.y); pk.u[2]=f2bf(b0.z); pk.u[3]=f2bf(b0.w);
  pk.u[4]=f2bf(b1.x); pk.u[5]=f2bf(b1.y); pk.u[6]=f2bf(b1.z); pk.u[7]=f2bf(b1.w);
  pk.u[8]=f2bf(b2.x); pk.u[9]=f2bf(b2.y); pk.u[10]=f2bf(b2.z); pk.u[11]=f2bf(b2.w);
  pk.u[12]=f2bf(b3.x); pk.u[13]=f2bf(b3.y); pk.u[14]=f2bf(b3.z); pk.u[15]=f2bf(b3.w);
  ((float4*)dst)[0] = pk.f[0];
  ((float4*)dst)[1] = pk.f[1];
}

// ---------------- RMSNorm (fp32 in, fp32 and/or bf16 out) ----------------
__global__ void rmsnorm_kernel(const float* __restrict__ x, const float* __restrict__ w,
                               float* __restrict__ out_f, u16* __restrict__ out_b) {
  int t = blockIdx.x;
  const float* row = x + (size_t)t * HID;
  float ss = 0.f;
  for (int c = threadIdx.x; c < HID; c += 256) { float v = row[c]; ss += v * v; }
  #pragma unroll
  for (int o = 32; o > 0; o >>= 1) ss += __shfl_down(ss, o, 64);
  __shared__ float red[4];
  __shared__ float sinv;
  int wid = threadIdx.x >> 6;
  if ((threadIdx.x & 63) == 0) red[wid] = ss;
  __syncthreads();
  if (threadIdx.x == 0) sinv = rsqrtf((red[0] + red[1] + red[2] + red[3]) * (1.f / HID) + EPSV);
  __syncthreads();
  float inv = sinv;
  for (int c = threadIdx.x; c < HID; c += 256) {
    float v = row[c] * inv * w[c];
    if (out_f) out_f[(size_t)t * HID + c] = v;
    if (out_b) out_b[(size_t)t * HID + c] = f2bf(v);
  }
}

// ---------------- fp32 GEMM: C[M,N] = A[M,K] @ B[N,K]^T (+R) ----------------
__global__ __launch_bounds__(256) void gemm_f32_bt(const float* __restrict__ A, const float* __restrict__ B,
    const float* __restrict__ R, float* __restrict__ C, int M, int N, int K) {
  __shared__ float Ast[16][64];
  __shared__ float Bst[16][64];
  int m0 = blockIdx.y * 64, n0 = blockIdx.x * 64;
  int tid = threadIdx.x;
  int tx = tid & 15, ty = tid >> 4;
  int lr = tid & 63;
  int lk = (tid >> 6) << 2;
  float acc[4][4];
  #pragma unroll
  for (int i = 0; i < 4; i++)
    #pragma unroll
    for (int j = 0; j < 4; j++) acc[i][j] = 0.f;
  const float* Ap = A + (size_t)(m0 + lr) * K + lk;
  const float* Bp = B + (size_t)(n0 + lr) * K + lk;
  for (int k0 = 0; k0 < K; k0 += 16) {
    __syncthreads();
    float4 av = *(const float4*)(Ap + k0);
    float4 bv = *(const float4*)(Bp + k0);
    Ast[lk + 0][lr] = av.x; Ast[lk + 1][lr] = av.y; Ast[lk + 2][lr] = av.z; Ast[lk + 3][lr] = av.w;
    Bst[lk + 0][lr] = bv.x; Bst[lk + 1][lr] = bv.y; Bst[lk + 2][lr] = bv.z; Bst[lk + 3][lr] = bv.w;
    __syncthreads();
    #pragma unroll
    for (int kk = 0; kk < 16; ++kk) {
      float4 a4 = *(const float4*)&Ast[kk][ty * 4];
      float4 b4 = *(const float4*)&Bst[kk][tx * 4];
      float aa[4] = {a4.x, a4.y, a4.z, a4.w};
      float bb[4] = {b4.x, b4.y, b4.z, b4.w};
      #pragma unroll
      for (int i = 0; i < 4; i++)
        #pragma unroll
        for (int j = 0; j < 4; j++) acc[i][j] = fmaf(aa[i], bb[j], acc[i][j]);
    }
  }
  #pragma unroll
  for (int i = 0; i < 4; i++) {
    size_t rowidx = (size_t)(m0 + ty * 4 + i) * N + n0 + tx * 4;
    #pragma unroll
    for (int j = 0; j < 4; j++) {
      float v = acc[i][j];
      if (R) v += R[rowidx + j];
      C[rowidx + j] = v;
    }
  }
}

// ---------------- RoPE (double-precision angles -> fp32 q/k; v passthrough) ----------------
__global__ void rope_kernel(const float* __restrict__ qkv, const int* __restrict__ pos,
                            float* __restrict__ qf, float* __restrict__ kf, float* __restrict__ vf) {
  int t = blockIdx.x;
  double p = (double)pos[t];
  const float* row = qkv + (size_t)t * 3072;
  const double LN = 0.21586735246819177; // ln(1e6)/64
  for (int i = threadIdx.x; i < 1024; i += 256) {
    int h = i >> 6, d = i & 63;
    double ang = p * exp(-LN * (double)d);
    float c = (float)cos(ang), s = (float)sin(ang);
    float x1 = row[h * 128 + d], x2 = row[h * 128 + 64 + d];
    qf[(size_t)t * 2048 + h * 128 + d]      = x1 * c - x2 * s;
    qf[(size_t)t * 2048 + h * 128 + 64 + d] = x2 * c + x1 * s;
  }
  for (int i = threadIdx.x; i < 256; i += 256) {
    int h = i >> 6, d = i & 63;
    double ang = p * exp(-LN * (double)d);
    float c = (float)cos(ang), s = (float)sin(ang);
    float x1 = row[2048 + h * 128 + d], x2 = row[2048 + h * 128 + 64 + d];
    kf[(size_t)t * 512 + h * 128 + d]      = x1 * c - x2 * s;
    kf[(size_t)t * 512 + h * 128 + 64 + d] = x2 * c + x1 * s;
  }
  for (int i = threadIdx.x; i < 512; i += 256) {
    vf[(size_t)t * 512 + i] = row[2560 + i];
  }
}

// ---------------- Flash attention, fp32, causal, GQA 4:1 ----------------
__global__ __launch_bounds__(256) void attn_kernel(const float* __restrict__ q, const float* __restrict__ k,
                                                   const float* __restrict__ v, float* __restrict__ o) {
  int qt = blockIdx.x, h = blockIdx.y;
  int q0 = qt * 64;
  int kvh = h >> 2;
  __shared__ float Qs[64 * 128];
  __shared__ float Ks[32 * 128];
  __shared__ float Vs[32 * 128];
  __shared__ float Ss[64 * 32];
  __shared__ float mrow[64], lrow[64], arow[64];
  int tid = threadIdx.x;
  for (int idx = tid; idx < 64 * 128; idx += 256) {
    int r = idx >> 7, d = idx & 127;
    Qs[idx] = q[(size_t)(q0 + r) * 2048 + h * 128 + d];
  }
  if (tid < 64) { mrow[tid] = -1e30f; lrow[tid] = 0.f; }
  float oacc[32];
  #pragma unroll
  for (int i = 0; i < 32; i++) oacc[i] = 0.f;
  int i = tid >> 2, jc = tid & 3;
  int nkt = (q0 + 64) >> 5;
  const float scale = 0.08838834764831845f;
  for (int kt = 0; kt < nkt; ++kt) {
    int j0 = kt << 5;
    __syncthreads();
    for (int idx = tid; idx < 32 * 128; idx += 256) {
      int r = idx >> 7, d = idx & 127;
      Ks[idx] = k[(size_t)(j0 + r) * 512 + kvh * 128 + d];
      Vs[idx] = v[(size_t)(j0 + r) * 512 + kvh * 128 + d];
    }
    __syncthreads();
    float sv[8];
    #pragma unroll
    for (int jj = 0; jj < 8; jj++) sv[jj] = 0.f;
    for (int d = 0; d < 128; d += 4) {
      float4 qv = *(const float4*)&Qs[i * 128 + d];
      #pragma unroll
      for (int jj = 0; jj < 8; jj++) {
        float4 kv = *(const float4*)&Ks[(jc * 8 + jj) * 128 + d];
        sv[jj] = fmaf(qv.x, kv.x, fmaf(qv.y, kv.y, fmaf(qv.z, kv.z, fmaf(qv.w, kv.w, sv[jj]))));
      }
    }
    int qrow = q0 + i;
    #pragma unroll
    for (int jj = 0; jj < 8; jj++) {
      int jg = j0 + jc * 8 + jj;
      Ss[i * 32 + jc * 8 + jj] = (jg <= qrow) ? sv[jj] * scale : -1e30f;
    }
    __syncthreads();
    if (jc == 0) {
      float mo = mrow[i], mx = mo;
      for (int j = 0; j < 32; j++) mx = fmaxf(mx, Ss[i * 32 + j]);
      float al = __expf(mo - mx);
      float sum = 0.f;
      for (int j = 0; j < 32; j++) { float pv = __expf(Ss[i * 32 + j] - mx); Ss[i * 32 + j] = pv; sum += pv; }
      lrow[i] = lrow[i] * al + sum; mrow[i] = mx; arow[i] = al;
    }
    __syncthreads();
    float al = arow[i];
    #pragma unroll
    for (int c = 0; c < 32; c++) oacc[c] *= al;
    for (int j = 0; j < 32; j++) {
      float pj = Ss[i * 32 + j];
      const float* vr = &Vs[j * 128 + jc * 32];
      #pragma unroll
      for (int c4 = 0; c4 < 8; c4++) {
        float4 vv = *(const float4*)(vr + c4 * 4);
        oacc[c4 * 4 + 0] = fmaf(pj, vv.x, oacc[c4 * 4 + 0]);
        oacc[c4 * 4 + 1] = fmaf(pj, vv.y, oacc[c4 * 4 + 1]);
        oacc[c4 * 4 + 2] = fmaf(pj, vv.z, oacc[c4 * 4 + 2]);
        oacc[c4 * 4 + 3] = fmaf(pj, vv.w, oacc[c4 * 4 + 3]);
      }
    }
  }
  __syncthreads();
  float linv = 1.f / lrow[i];
  for (int c = 0; c < 32; c++)
    o[(size_t)(q0 + i) * 2048 + h * 128 + jc * 32 + c] = oacc[c] * linv;
}

// ---------------- Router: logits, softmax, top2, atomic expert lists ----------------
__global__ void router_kernel(const float* __restrict__ h2, const float* __restrict__ gw,
                              int* __restrict__ cnt, int* __restrict__ ent, float* __restrict__ ewt) {
  int t = blockIdx.x;
  int lane = threadIdx.x; // blockDim = 64
  float lg[NE];
  #pragma unroll
  for (int e = 0; e < NE; e++) lg[e] = 0.f;
  const float* hr = h2 + (size_t)t * HID;
  for (int c = lane; c < HID; c += 64) {
    float hv = hr[c];
    #pragma unroll
    for (int e = 0; e < NE; e++) lg[e] = fmaf(hv, gw[e * HID + c], lg[e]);
  }
  #pragma unroll
  for (int e = 0; e < NE; e++) {
    #pragma unroll
    for (int o = 32; o > 0; o >>= 1) lg[e] += __shfl_down(lg[e], o, 64);
  }
  if (lane == 0) {
    float mx = lg[0];
    for (int e = 1; e < NE; e++) mx = fmaxf(mx, lg[e]);
    float pe[NE]; float se = 0.f;
    for (int e = 0; e < NE; e++) { pe[e] = __expf(lg[e] - mx); se += pe[e]; }
    int i0 = 0;
    for (int e = 1; e < NE; e++) if (pe[e] > pe[i0]) i0 = e;
    int i1 = (i0 == 0) ? 1 : 0;
    for (int e = 0; e < NE; e++) { if (e == i0) continue; if (pe[e] > pe[i1]) i1 = e; }
    float w0 = pe[i0], w1 = pe[i1];
    float s = w0 + w1; w0 /= s; w1 /= s;
    int p0 = atomicAdd(&cnt[i0], 1);
    ent[i0 * T_SEQ + p0] = t * 2;     ewt[i0 * T_SEQ + p0] = w0;
    int p1 = atomicAdd(&cnt[i1], 1);
    ent[i1 * T_SEQ + p1] = t * 2 + 1; ewt[i1 * T_SEQ + p1] = w1;
  }
}

// ---------------- MoE GEMM13: ge = silu(X@w1^T) * (X@w3^T), bf16 MFMA ----------------
__global__ __launch_bounds__(256) void gemm13_kernel(const u16* __restrict__ h2b, const float* __restrict__ w1,
    const float* __restrict__ w3, const int* __restrict__ cnt, const int* __restrict__ ent,
    u16* __restrict__ ge) {
  int e = blockIdx.z;
  int me = cnt[e];
  int m0 = blockIdx.y * 128;
  if (m0 >= me) return;
  int n0 = blockIdx.x * 64;
  __shared__ __align__(16) u16 As[128 * 32];
  __shared__ __align__(16) u16 B1s[64 * 32];
  __shared__ __align__(16) u16 B3s[64 * 32];
  __shared__ int rowent[128];
  int tid = threadIdx.x;
  const int* el = ent + e * T_SEQ;
  if (tid < 128) {
    int i = m0 + tid;
    rowent[tid] = el[i < me ? i : me - 1];
  }
  int wave = tid >> 6, lane = tid & 63;
  int wm = wave >> 1, wn = wave & 1;
  f32x4 zero = {0.f, 0.f, 0.f, 0.f};
  f32x4 acc1[4][2], acc3[4][2];
  #pragma unroll
  for (int mt = 0; mt < 4; mt++)
    #pragma unroll
    for (int nt = 0; nt < 2; nt++) { acc1[mt][nt] = zero; acc3[mt][nt] = zero; }
  int arow = tid >> 1, ahalf = tid & 1;
  int brow = (tid & 127) >> 1, bhalf = tid & 1;
  const float* wsel = (tid >= 128) ? w3 : w1;
  u16* bdst = (tid >= 128) ? B3s : B1s;
  int lm = lane & 15, lk8 = (lane >> 4) * 8;
  for (int k0 = 0; k0 < HID; k0 += 32) {
    __syncthreads();
    {
      int tok = rowent[arow] >> 1;
      stage_a16(h2b + (size_t)tok * HID + k0 + ahalf * 16, &As[arow * 32 + ahalf * 16]);
    }
    stage_b16(wsel + ((size_t)e * FFN + n0 + brow) * HID + k0 + bhalf * 16,
              &bdst[brow * 32 + bhalf * 16]);
    __syncthreads();
    bf16x8 af[4], b1f[2], b3f[2];
    #pragma unroll
    for (int mt = 0; mt < 4; mt++)
      af[mt] = *(const bf16x8*)&As[(wm * 64 + mt * 16 + lm) * 32 + lk8];
    #pragma unroll
    for (int nt = 0; nt < 2; nt++) {
      b1f[nt] = *(const bf16x8*)&B1s[(wn * 32 + nt * 16 + lm) * 32 + lk8];
      b3f[nt] = *(const bf16x8*)&B3s[(wn * 32 + nt * 16 + lm) * 32 + lk8];
    }
    #pragma unroll
    for (int mt = 0; mt < 4; mt++)
      #pragma unroll
      for (int nt = 0; nt < 2; nt++) {
        acc1[mt][nt] = __builtin_amdgcn_mfma_f32_16x16x32_bf16(af[mt], b1f[nt], acc1[mt][nt], 0, 0, 0);
        acc3[mt][nt] = __builtin_amdgcn_mfma_f32_16x16x32_bf16(af[mt], b3f[nt], acc3[mt][nt], 0, 0, 0);
      }
  }
  int col = lane & 15;
  #pragma unroll
  for (int mt = 0; mt < 4; mt++) {
    #pragma unroll
    for (int j = 0; j < 4; j++) {
      int r = wm * 64 + mt * 16 + (lane >> 4) * 4 + j;
      if (m0 + r < me) {
        int en = rowent[r];
        #pragma unroll
        for (int nt = 0; nt < 2; nt++) {
          float a = acc1[mt][nt][j], b = acc3[mt][nt][j];
          float sl = a / (1.f + __expf(-a));
          ge[(size_t)en * FFN + n0 + wn * 32 + nt * 16 + col] = f2bf(sl * b);
        }
      }
    }
  }
}

// ---------------- MoE GEMM2: moe[ent] = w * (ge @ w2^T), bf16 MFMA ----------------
__global__ __launch_bounds__(256) void gemm2_kernel(const u16* __restrict__ ge, const float* __restrict__ w2,
    const int* __restrict__ cnt, const int* __restrict__ ent, const float* __restrict__ ewt,
    float* __restrict__ moe) {
  int e = blockIdx.z;
  int me = cnt[e];
  int m0 = blockIdx.y * 128;
  if (m0 >= me) return;
  int n0 = blockIdx.x * 128;
  __shared__ __align__(16) u16 As[128 * 32];
  __shared__ __align__(16) u16 Bs[128 * 32];
  __shared__ int rowent[128];
  __shared__ float roww[128];
  int tid = threadIdx.x;
  const int* el = ent + e * T_SEQ;
  if (tid < 128) {
    int i = m0 + tid;
    int ic = i < me ? i : me - 1;
    rowent[tid] = el[ic];
    roww[tid] = ewt[e * T_SEQ + ic];
  }
  int wave = tid >> 6, lane = tid & 63;
  int wm = wave >> 1, wn = wave & 1;
  f32x4 zero = {0.f, 0.f, 0.f, 0.f};
  f32x4 acc[4][4];
  #pragma unroll
  for (int mt = 0; mt < 4; mt++)
    #pragma unroll
    for (int nt = 0; nt < 4; nt++) acc[mt][nt] = zero;
  int arow = tid >> 1, ahalf = tid & 1;
  int lm = lane & 15, lk8 = (lane >> 4) * 8;
  for (int k0 = 0; k0 < FFN; k0 += 32) {
    __syncthreads();
    {
      int en = rowent[arow];
      stage_a16(ge + (size_t)en * FFN + k0 + ahalf * 16, &As[arow * 32 + ahalf * 16]);
    }
    stage_b16(w2 + ((size_t)e * HID + n0 + arow) * FFN + k0 + ahalf * 16,
              &Bs[arow * 32 + ahalf * 16]);
    __syncthreads();
    bf16x8 af[4], bf_[4];
    #pragma unroll
    for (int mt = 0; mt < 4; mt++)
      af[mt] = *(const bf16x8*)&As[(wm * 64 + mt * 16 + lm) * 32 + lk8];
    #pragma unroll
    for (int nt = 0; nt < 4; nt++)
      bf_[nt] = *(const bf16x8*)&Bs[(wn * 64 + nt * 16 + lm) * 32 + lk8];
    #pragma unroll
    for (int mt = 0; mt < 4; mt++)
      #pragma unroll
      for (int nt = 0; nt < 4; nt++)
        acc[mt][nt] = __builtin_amdgcn_mfma_f32_16x16x32_bf16(af[mt], bf_[nt], acc[mt][nt], 0, 0, 0);
  }
  int col = lane & 15;
  #pragma unroll
  for (int mt = 0; mt < 4; mt++) {
    #pragma unroll
    for (int j = 0; j < 4; j++) {
      int r = wm * 64 + mt * 16 + (lane >> 4) * 4 + j;
      if (m0 + r < me) {
        int en = rowent[r];
        float w = roww[r];
        #pragma unroll
        for (int nt = 0; nt < 4; nt++)
          moe[(size_t)en * HID + n0 + wn * 64 + nt * 16 + col] = w * acc[mt][nt][j];
      }
    }
  }
}

// ---------------- Final: out = resid2 + moe_slot0 + moe_slot1 ----------------
__global__ void final_kernel(const float* __restrict__ resid2, const float* __restrict__ moe,
                             float* __restrict__ out) {
  size_t idx = (size_t)blockIdx.x * 256 + threadIdx.x;
  size_t t = idx >> 11;
  size_t c = idx & 2047;
  out[idx] = resid2[idx] + moe[(t * 2) * HID + c] + moe[(t * 2 + 1) * HID + c];
}

extern "C" void kernel_launch(void* const* d_in, const int* in_sizes, int n_in,
                              void* d_out, int out_size, void* d_ws, size_t ws_size,
                              hipStream_t stream) {
  const float* hs   = (const float*)d_in[0];
  const int*   pos  = (const int*)d_in[1];
  const float* ln1  = (const float*)d_in[2];
  const float* ln2  = (const float*)d_in[3];
  const float* wqkv = (const float*)d_in[4];
  const float* wo   = (const float*)d_in[5];
  const float* gatew= (const float*)d_in[6];
  const float* w1   = (const float*)d_in[7];
  const float* w2   = (const float*)d_in[8];
  const float* w3   = (const float*)d_in[9];
  float* out = (float*)d_out;

  char* p = (char*)d_ws;
  auto alloc = [&](size_t bytes) { char* r = p; p += (bytes + 255) & ~(size_t)255; return r; };
  float* h1f    = (float*)alloc((size_t)T_SEQ * HID * 4);
  float* qkv    = (float*)alloc((size_t)T_SEQ * 3072 * 4);
  float* qf     = (float*)alloc((size_t)T_SEQ * 2048 * 4);
  float* kf     = (float*)alloc((size_t)T_SEQ * 512 * 4);
  float* vf     = (float*)alloc((size_t)T_SEQ * 512 * 4);
  float* of     = (float*)alloc((size_t)T_SEQ * 2048 * 4);
  float* resid2 = (float*)alloc((size_t)T_SEQ * HID * 4);
  float* h2f    = (float*)alloc((size_t)T_SEQ * HID * 4);
  u16*   h2b    = (u16*)alloc((size_t)T_SEQ * HID * 2);
  int*   cnt    = (int*)alloc(NE * 4);
  int*   ent    = (int*)alloc((size_t)NE * T_SEQ * 4);
  float* ewt    = (float*)alloc((size_t)NE * T_SEQ * 4);
  u16*   geb    = (u16*)alloc((size_t)T_SEQ * 2 * FFN * 2);
  float* moe    = (float*)alloc((size_t)T_SEQ * 2 * HID * 4);

  rmsnorm_kernel<<<T_SEQ, 256, 0, stream>>>(hs, ln1, h1f, nullptr);
  gemm_f32_bt<<<dim3(3072 / 64, 2048 / 64), 256, 0, stream>>>(h1f, wqkv, nullptr, qkv, 2048, 3072, 2048);
  rope_kernel<<<T_SEQ, 256, 0, stream>>>(qkv, pos, qf, kf, vf);
  attn_kernel<<<dim3(32, 16), 256, 0, stream>>>(qf, kf, vf, of);
  gemm_f32_bt<<<dim3(2048 / 64, 2048 / 64), 256, 0, stream>>>(of, wo, hs, resid2, 2048, 2048, 2048);
  rmsnorm_kernel<<<T_SEQ, 256, 0, stream>>>(resid2, ln2, h2f, h2b);
  hipMemsetAsync(cnt, 0, NE * 4, stream);
  router_kernel<<<T_SEQ, 64, 0, stream>>>(h2f, gatew, cnt, ent, ewt);
  gemm13_kernel<<<dim3(FFN / 64, 16, NE), 256, 0, stream>>>(h2b, w1, w3, cnt, ent, geb);
  gemm2_kernel<<<dim3(HID / 128, 16, NE), 256, 0, stream>>>(geb, w2, cnt, ent, ewt, moe);
  final_kernel<<<(T_SEQ * HID) / 256, 256, 0, stream>>>(resid2, moe, out);
}